// Round 2
// baseline (1585.201 us; speedup 1.0000x reference)
//
#include <hip/hip_runtime.h>
#include <hip/hip_cooperative_groups.h>

namespace cg = cooperative_groups;

#define EPS 1e-4f
constexpr int N_DIM  = 1024;
constexpr int M_DIM  = 1024;
constexpr int BATCH  = 64;
constexpr int MAXGRID = 1024;   // 256 CU x 4 blocks/CU

// One persistent cooperative kernel: 10 alternating col/row normalization
// sweeps (rank-1 factor form: out = r[n]*(s+EPS)*c[m]) + fused finalize.
// All phases are grid-stride loops so any grid size <= MAXGRID is correct.
__global__ __launch_bounds__(256, 4)
void sinkhorn_fused(const float* __restrict__ s,
                    const int* __restrict__ nrows,
                    const int* __restrict__ ncols,
                    float* __restrict__ r,
                    float* __restrict__ c,
                    float* __restrict__ out)
{
    cg::grid_group grid = cg::this_grid();
    const int tid  = threadIdx.x;
    const int lane = tid & 63;
    const int wv   = tid >> 6;          // 0..3
    const int nblk = gridDim.x;

    __shared__ float red[4][64];

    for (int iter = 0; iter < 10; ++iter) {
        if ((iter & 1) == 0) {
            // col sums: c[b][m] = 1 / sum_{n<R} r[n]*(s+EPS); iter0 => r==1
            // units: BATCH x 16 tiles of 64 cols
            for (int u = blockIdx.x; u < BATCH * 16; u += nblk) {
                const int b  = u >> 4;
                const int m0 = (u & 15) * 64;
                const int C  = ncols[b];
                if (m0 < C) {
                    const int R = nrows[b];
                    const int m = m0 + lane;
                    const float* __restrict__ sb = s + (size_t)b * N_DIM * M_DIM;
                    const float* __restrict__ rb = r + b * N_DIM;
                    float sum = 0.f;
                    if (iter == 0) {
#pragma unroll 4
                        for (int n = wv; n < R; n += 4)
                            sum += sb[(size_t)n * M_DIM + m] + EPS;
                    } else {
#pragma unroll 4
                        for (int n = wv; n < R; n += 4)
                            sum += rb[n] * (sb[(size_t)n * M_DIM + m] + EPS);
                    }
                    red[wv][lane] = sum;
                    __syncthreads();
                    if (wv == 0 && m < C) {
                        float t = red[0][lane] + red[1][lane] + red[2][lane] + red[3][lane];
                        c[b * M_DIM + m] = (t == 0.f) ? 1.f : 1.f / t;
                    }
                    __syncthreads();
                }
            }
        } else {
            // row sums: r[b][n] = 1 / sum_{m<C} c[m]*(s+EPS)
            // units: BATCH x 16 chunks of 64 rows; 1 row per wave at a time
            for (int u = blockIdx.x; u < BATCH * 16; u += nblk) {
                const int b  = u >> 4;
                const int n0 = (u & 15) * 64;
                const int R  = nrows[b];
                if (n0 >= R) continue;
                const int C  = ncols[b];
                const int C4 = C >> 2;
                const float* __restrict__ sb = s + (size_t)b * N_DIM * M_DIM;
                const float* __restrict__ cb = c + b * M_DIM;
                for (int i = 0; i < 16; ++i) {
                    const int n = n0 + wv * 16 + i;
                    if (n >= R) break;                 // rows increase with i
                    const float* __restrict__ srow = sb + (size_t)n * M_DIM;
                    const float4* __restrict__ s4 = (const float4*)srow;
                    const float4* __restrict__ c4 = (const float4*)cb;
                    float sum = 0.f;
                    for (int j = lane; j < C4; j += 64) {
                        float4 v = s4[j], cc = c4[j];
                        sum += (v.x + EPS) * cc.x + (v.y + EPS) * cc.y +
                               (v.z + EPS) * cc.z + (v.w + EPS) * cc.w;
                    }
                    for (int mm = (C4 << 2) + lane; mm < C; mm += 64)
                        sum += (srow[mm] + EPS) * cb[mm];
#pragma unroll
                    for (int off = 32; off; off >>= 1)
                        sum += __shfl_down(sum, off);
                    if (lane == 0)
                        r[b * N_DIM + n] = (sum == 0.f) ? 1.f : 1.f / sum;
                }
            }
        }
        grid.sync();
    }

    // finalize: out = (n<R && m<C) ? (s+EPS)*r[n]*c[m] : 0
    for (int row = blockIdx.x; row < BATCH * N_DIM; row += nblk) {
        const int b = row >> 10;
        const int n = row & (N_DIM - 1);
        const int R = nrows[b], C = ncols[b];
        const size_t base = (size_t)row * M_DIM;
        const int m = tid * 4;                        // 256 thr x 4 = 1024 = M
        float4 o = make_float4(0.f, 0.f, 0.f, 0.f);
        if (n < R && m < C) {
            const float rn = r[b * N_DIM + n];
            float4 v  = *(const float4*)(s + base + m);
            float4 cc = *(const float4*)(c + b * M_DIM + m);
            o.x = (m + 0 < C) ? (v.x + EPS) * rn * cc.x : 0.f;
            o.y = (m + 1 < C) ? (v.y + EPS) * rn * cc.y : 0.f;
            o.z = (m + 2 < C) ? (v.z + EPS) * rn * cc.z : 0.f;
            o.w = (m + 3 < C) ? (v.w + EPS) * rn * cc.w : 0.f;
        }
        *(float4*)(out + base + m) = o;
    }
}

extern "C" void kernel_launch(void* const* d_in, const int* in_sizes, int n_in,
                              void* d_out, int out_size, void* d_ws, size_t ws_size,
                              hipStream_t stream) {
    const float* s     = (const float*)d_in[0];
    const int*   nrows = (const int*)d_in[1];
    const int*   ncols = (const int*)d_in[2];
    float*       out   = (float*)d_out;

    float* r = (float*)d_ws;                       // BATCH * N floats
    float* c = r + (size_t)BATCH * N_DIM;          // BATCH * M floats

    int dev = 0;
    hipGetDevice(&dev);
    int numCU = 0;
    hipDeviceGetAttribute(&numCU, hipDeviceAttributeMultiprocessorCount, dev);
    int perCU = 0;
    hipOccupancyMaxActiveBlocksPerMultiprocessor(&perCU, sinkhorn_fused, 256, 0);
    int grid = perCU * numCU;
    if (grid > MAXGRID) grid = MAXGRID;
    if (grid < 1)       grid = 1;

    void* args[] = {(void*)&s, (void*)&nrows, (void*)&ncols,
                    (void*)&r, (void*)&c, (void*)&out};
    hipLaunchCooperativeKernel((void*)sinkhorn_fused, dim3(grid), dim3(256),
                               args, 0, stream);
}

// Round 3
// 244.312 us; speedup vs baseline: 6.4884x; 6.4884x over previous
//
#include <hip/hip_runtime.h>

#define EPS 1e-4f
constexpr int N_DIM = 1024;
constexpr int M_DIM = 1024;
constexpr int BATCH = 64;

// Factor form: after any prefix of iterations, out = r[n]*(s+EPS)*c[m].
// col sweep k:  traw[m] = sum_{n<R} r[n]*(s+EPS)   (r = 1/uraw from prev row sweep)
// row sweep k:  uraw[n] = sum_{m<C} c[m]*(s+EPS)   (c = 1/traw)
// finalize:     out = (1/uraw)[n] * (s+EPS) * (1/traw)[m] inside block, else 0.

// ---------------------------------------------------------------------------
// col sweep: grid (4 mtiles * CHUNKS, B), 256 thr = 4 waves.
// Lane owns 4 consecutive cols (float4); waves stride rows within the chunk.
// Writes per-chunk partial sums tpart[ch][b][m] (always, so no zero-init).
// ---------------------------------------------------------------------------
template <bool FIRST, int CHUNKS>
__global__ __launch_bounds__(256)
void col_sweep(const float* __restrict__ s,
               const int* __restrict__ nrows,
               const int* __restrict__ ncols,
               const float* __restrict__ u,     // raw row sums (invert here)
               float* __restrict__ tpart) {
    const int b  = blockIdx.y;
    const int mt = blockIdx.x & 3;          // 4 tiles of 256 cols
    const int ch = blockIdx.x >> 2;         // n-chunk
    const int R = nrows[b], C = ncols[b];
    const int lane = threadIdx.x & 63, wv = threadIdx.x >> 6;
    const int m0 = mt * 256;
    const int m  = m0 + lane * 4;

    constexpr int ROWS = N_DIM / CHUNKS;
    const int n0 = ch * ROWS;
    const int nend = min(R, n0 + ROWS);

    __shared__ float rlds[1024];            // 1/u for this chunk's rows
    if (!FIRST) {
        for (int i = threadIdx.x; i < ROWS; i += 256) {
            float uu = u[b * N_DIM + n0 + i];
            rlds[i] = (uu == 0.f) ? 1.f : 1.f / uu;
        }
        __syncthreads();
    }

    float4 acc = make_float4(0.f, 0.f, 0.f, 0.f);
    if (m0 < C) {                           // block-uniform
        const float* __restrict__ sb = s + (size_t)b * N_DIM * M_DIM;
#pragma unroll 4
        for (int n = n0 + wv; n < nend; n += 4) {
            float4 v = *(const float4*)(sb + (size_t)n * M_DIM + m);
            float rn = FIRST ? 1.f : rlds[n - n0];
            acc.x += rn * (v.x + EPS);
            acc.y += rn * (v.y + EPS);
            acc.z += rn * (v.z + EPS);
            acc.w += rn * (v.w + EPS);
        }
    }

    __shared__ float4 red[4][64];
    red[wv][lane] = acc;
    __syncthreads();
    if (wv == 0) {
        float4 a0 = red[0][lane], a1 = red[1][lane],
               a2 = red[2][lane], a3 = red[3][lane];
        float4 t = make_float4(a0.x + a1.x + a2.x + a3.x,
                               a0.y + a1.y + a2.y + a3.y,
                               a0.z + a1.z + a2.z + a3.z,
                               a0.w + a1.w + a2.w + a3.w);
        *(float4*)(tpart + ((size_t)(ch * BATCH + b)) * M_DIM + m) = t;
    }
}

// ---------------------------------------------------------------------------
// row sweep: grid (64 nchunks of 16 rows, B), 256 thr = 4 waves x 4 rows.
// Prep: c = 1/(sum of CHUNKS partials) into LDS (and to global on last sweep).
// ---------------------------------------------------------------------------
template <int CHUNKS, bool WRITE_C>
__global__ __launch_bounds__(256)
void row_sweep(const float* __restrict__ s,
               const int* __restrict__ nrows,
               const int* __restrict__ ncols,
               const float* __restrict__ tpart,
               float* __restrict__ u,           // raw row sums out
               float* __restrict__ cOut) {
    const int b = blockIdx.y;
    const int R = nrows[b], C = ncols[b];
    const int n0 = blockIdx.x * 16;
    if (n0 >= R) return;

    __shared__ float clds[M_DIM];
    {
        const int t4 = threadIdx.x;              // 256 thr x float4 = 1024
        float4 sum = make_float4(0.f, 0.f, 0.f, 0.f);
#pragma unroll
        for (int ch = 0; ch < CHUNKS; ++ch) {
            float4 p = *(const float4*)(tpart + ((size_t)(ch * BATCH + b)) * M_DIM + t4 * 4);
            sum.x += p.x; sum.y += p.y; sum.z += p.z; sum.w += p.w;
        }
        float4 cv;
        cv.x = (sum.x == 0.f) ? 1.f : 1.f / sum.x;
        cv.y = (sum.y == 0.f) ? 1.f : 1.f / sum.y;
        cv.z = (sum.z == 0.f) ? 1.f : 1.f / sum.z;
        cv.w = (sum.w == 0.f) ? 1.f : 1.f / sum.w;
        *(float4*)&clds[t4 * 4] = cv;
        if (WRITE_C && blockIdx.x == 0)
            *(float4*)(cOut + b * M_DIM + t4 * 4) = cv;
    }
    __syncthreads();

    const int lane = threadIdx.x & 63, wv = threadIdx.x >> 6;
    const int C4 = C >> 2;
#pragma unroll
    for (int i = 0; i < 4; ++i) {
        const int n = n0 + wv * 4 + i;
        if (n >= R) break;
        const float* __restrict__ srow = s + ((size_t)b * N_DIM + n) * M_DIM;
        float sum = 0.f;
        for (int j = lane; j < C4; j += 64) {
            float4 v  = ((const float4*)srow)[j];
            float4 cc = *(const float4*)&clds[j * 4];
            sum += (v.x + EPS) * cc.x + (v.y + EPS) * cc.y +
                   (v.z + EPS) * cc.z + (v.w + EPS) * cc.w;
        }
        for (int mm = (C4 << 2) + lane; mm < C; mm += 64)
            sum += (srow[mm] + EPS) * clds[mm];
#pragma unroll
        for (int off = 32; off; off >>= 1) sum += __shfl_down(sum, off);
        if (lane == 0) u[b * N_DIM + n] = sum;     // raw (consumers invert)
    }
}

// ---------------------------------------------------------------------------
// finalize: grid (N, B), 256 thr, float4 per thread.
// out = (n<R && m<C) ? (s+EPS) * (1/u[n]) * c[m] : 0
// ---------------------------------------------------------------------------
__global__ __launch_bounds__(256)
void finalize(const float* __restrict__ s,
              const int* __restrict__ nrows,
              const int* __restrict__ ncols,
              const float* __restrict__ u,
              const float* __restrict__ c,
              float* __restrict__ out) {
    const int n = blockIdx.x;
    const int b = blockIdx.y;
    const int R = nrows[b], C = ncols[b];
    const size_t base = ((size_t)b * N_DIM + n) * M_DIM;
    const int m = threadIdx.x * 4;

    float4 o = make_float4(0.f, 0.f, 0.f, 0.f);
    if (n < R && m < C) {
        float uu = u[b * N_DIM + n];               // block-uniform load
        float rn = (uu == 0.f) ? 1.f : 1.f / uu;
        float4 v  = *(const float4*)(s + base + m);
        float4 cc = *(const float4*)(c + b * M_DIM + m);
        o.x = (m + 0 < C) ? (v.x + EPS) * rn * cc.x : 0.f;
        o.y = (m + 1 < C) ? (v.y + EPS) * rn * cc.y : 0.f;
        o.z = (m + 2 < C) ? (v.z + EPS) * rn * cc.z : 0.f;
        o.w = (m + 3 < C) ? (v.w + EPS) * rn * cc.w : 0.f;
    }
    *(float4*)(out + base + m) = o;
}

extern "C" void kernel_launch(void* const* d_in, const int* in_sizes, int n_in,
                              void* d_out, int out_size, void* d_ws, size_t ws_size,
                              hipStream_t stream) {
    const float* s     = (const float*)d_in[0];
    const int*   nrows = (const int*)d_in[1];
    const int*   ncols = (const int*)d_in[2];
    float*       out   = (float*)d_out;

    // ws layout: tpart[CHUNKS][B][M] | u[B][N] | c[B][M]
    const size_t needed4 = (size_t)(4 * BATCH * M_DIM + BATCH * N_DIM + BATCH * M_DIM) * 4;
    const bool big = ws_size >= needed4;

    if (big) {
        constexpr int CH = 4;
        float* tpart = (float*)d_ws;
        float* u = tpart + (size_t)CH * BATCH * M_DIM;
        float* c = u + (size_t)BATCH * N_DIM;
        dim3 colGrid(4 * CH, BATCH), rowGrid(64, BATCH);
        col_sweep<true, CH><<<colGrid, 256, 0, stream>>>(s, nrows, ncols, u, tpart);
        row_sweep<CH, false><<<rowGrid, 256, 0, stream>>>(s, nrows, ncols, tpart, u, c);
        for (int k = 1; k < 4; ++k) {
            col_sweep<false, CH><<<colGrid, 256, 0, stream>>>(s, nrows, ncols, u, tpart);
            row_sweep<CH, false><<<rowGrid, 256, 0, stream>>>(s, nrows, ncols, tpart, u, c);
        }
        col_sweep<false, CH><<<colGrid, 256, 0, stream>>>(s, nrows, ncols, u, tpart);
        row_sweep<CH, true><<<rowGrid, 256, 0, stream>>>(s, nrows, ncols, tpart, u, c);
        finalize<<<dim3(N_DIM, BATCH), 256, 0, stream>>>(s, nrows, ncols, u, c, out);
    } else {
        constexpr int CH = 1;
        float* tpart = (float*)d_ws;
        float* u = tpart + (size_t)CH * BATCH * M_DIM;
        float* c = u + (size_t)BATCH * N_DIM;
        dim3 colGrid(4 * CH, BATCH), rowGrid(64, BATCH);
        col_sweep<true, CH><<<colGrid, 256, 0, stream>>>(s, nrows, ncols, u, tpart);
        row_sweep<CH, false><<<rowGrid, 256, 0, stream>>>(s, nrows, ncols, tpart, u, c);
        for (int k = 1; k < 4; ++k) {
            col_sweep<false, CH><<<colGrid, 256, 0, stream>>>(s, nrows, ncols, u, tpart);
            row_sweep<CH, false><<<rowGrid, 256, 0, stream>>>(s, nrows, ncols, tpart, u, c);
        }
        col_sweep<false, CH><<<colGrid, 256, 0, stream>>>(s, nrows, ncols, u, tpart);
        row_sweep<CH, true><<<rowGrid, 256, 0, stream>>>(s, nrows, ncols, tpart, u, c);
        finalize<<<dim3(N_DIM, BATCH), 256, 0, stream>>>(s, nrows, ncols, u, c, out);
    }
}